// Round 7
// baseline (127.290 us; speedup 1.0000x reference)
//
#include <hip/hip_runtime.h>
#include <hip/hip_bf16.h>
#include <stdint.h>

#define NROWS 4096
#define DIM   1024
#define NCLS  64
#define NTB   32            // 4096/128 tile-blocks per axis
#define NTRI  528           // 32*33/2 upper-triangle tiles (= 8 * 66)
#define CONV_BLOCKS 2048    // convert part of fused prep kernel
#define PREP_BLOCKS 1024

constexpr float TEMP_INV = 1.0f / 0.07f;

typedef __attribute__((ext_vector_type(8))) short  bf16x8;
typedef __attribute__((ext_vector_type(4))) float  f32x4;

__device__ inline void gload_lds16(const void* g, void* l) {
    __builtin_amdgcn_global_load_lds(
        (const __attribute__((address_space(1))) void*)g,
        (__attribute__((address_space(3))) void*)l, 16, 0, 0);
}

// ---------------- kernel 1: fused convert (bf16 pre-swizzle) + prep ----------
// swizzle: within each 64B block (4x 16B slots) of a row, slot s stored at
// s ^ ((row>>1)&3)  -- matched by frag_read's XOR. (row>>1 key: <=2-way banks)
__global__ void prep_convert_kernel(const float* __restrict__ emb,
                                    const float* __restrict__ logits,
                                    const int* __restrict__ labels,
                                    __hip_bfloat16* __restrict__ embb,
                                    uint64_t* __restrict__ maskout,
                                    float* __restrict__ wout,
                                    float* __restrict__ bceout,
                                    float* __restrict__ psum,
                                    float* __restrict__ nsum) {
    const int b = blockIdx.x;
    if (b < CONV_BLOCKS) {
        const int t   = b * 256 + threadIdx.x;   // one 16B slot (8 elems) each
        const int row = t >> 7;                  // 128 slots per row
        const int u   = t & 127;
        const int b32 = u >> 2;                  // 32-elem K-block
        const int s2  = u & 3;                   // slot within block
        const float* src = emb + (size_t)row * DIM + b32 * 32 + s2 * 8;
        const float4 a  = *(const float4*)src;
        const float4 bb = *(const float4*)(src + 4);
        const int sd = s2 ^ ((row >> 1) & 3);
        union { __hip_bfloat16 h[8]; float4 v; } uv;
        uv.h[0] = __float2bfloat16(a.x);  uv.h[1] = __float2bfloat16(a.y);
        uv.h[2] = __float2bfloat16(a.z);  uv.h[3] = __float2bfloat16(a.w);
        uv.h[4] = __float2bfloat16(bb.x); uv.h[5] = __float2bfloat16(bb.y);
        uv.h[6] = __float2bfloat16(bb.z); uv.h[7] = __float2bfloat16(bb.w);
        *(float4*)(embb + (size_t)row * DIM + b32 * 32 + sd * 8) = uv.v;
    } else {
        const int pb   = b - CONV_BLOCKS;
        const int row  = pb * 4 + (threadIdx.x >> 6);
        const int lane = threadIdx.x & 63;
        if (threadIdx.x < 4)       psum[pb * 4 + threadIdx.x] = 0.0f;
        else if (threadIdx.x < 8)  nsum[pb * 4 + threadIdx.x - 4] = 0.0f;

        const float l = logits[row * NCLS + lane];
        const int   y = labels[row * NCLS + lane];
        const float yf = (float)y;

        float bce = fmaxf(l, 0.0f) - l * yf + log1pf(expf(-fabsf(l)));
        const float pr = 1.0f / (1.0f + expf(-l));
        const float ent = -(pr * logf(pr + 1e-8f) + (1.0f - pr) * logf(1.0f - pr + 1e-8f));
        float entw = ent * yf;
        float ycnt = yf;

        #pragma unroll
        for (int off = 32; off; off >>= 1) {
            bce  += __shfl_down(bce, off);
            entw += __shfl_down(entw, off);
            ycnt += __shfl_down(ycnt, off);
        }
        const uint64_t m = __ballot(y != 0);
        if (lane == 0) {
            maskout[row] = m;
            wout[row]    = entw / (ycnt + 1e-8f);
            bceout[row]  = bce;
        }
    }
}

// ---------------- kernel 2: MFMA sim tiles, 3-deep single-barrier pipeline ---
// LDS tile: [128 rows][32 bf16] = 8 KB, row stride 64 B, slots swizzled.
__device__ inline bf16x8 frag_read(const unsigned char* tile, int row, int lane) {
    const int slot = (lane >> 4) ^ ((row >> 1) & 3);
    return *(const bf16x8*)(tile + row * 64 + slot * 16);
}

// 512 threads: 2 loads/thread (1 A + 1 B). buf layout: A at +0 (8KB), B at +8192.
__device__ inline void stage_tile(const __hip_bfloat16* __restrict__ embb,
                                  size_t arow0, size_t brow0, int kb,
                                  unsigned char* buf, int tid) {
    const int r = tid >> 2;            // 0..127
    const int s = (tid & 3) * 8;       // elem offset (pre-swizzled source)
    gload_lds16(embb + (arow0 + r) * DIM + kb * 32 + s, buf + tid * 16);
    gload_lds16(embb + (brow0 + r) * DIM + kb * 32 + s, buf + 8192 + tid * 16);
}

// wave (wm,wn) computes 64x32 sub-tile: acc[4 row-frags][2 col-frags], 1 k-step
__device__ inline void compute_tile(const unsigned char* buf,
                                    int wm, int wn, int lane, f32x4 acc[4][2]) {
    const unsigned char* As = buf;
    const unsigned char* Bs = buf + 8192;
    __builtin_amdgcn_s_setprio(1);
    bf16x8 af[4], bfr[2];
    #pragma unroll
    for (int f = 0; f < 4; ++f)
        af[f] = frag_read(As, wm * 64 + f * 16 + (lane & 15), lane);
    #pragma unroll
    for (int g = 0; g < 2; ++g)
        bfr[g] = frag_read(Bs, wn * 32 + g * 16 + (lane & 15), lane);
    #pragma unroll
    for (int i = 0; i < 4; ++i)
        #pragma unroll
        for (int j = 0; j < 2; ++j)
            acc[i][j] = __builtin_amdgcn_mfma_f32_16x16x32_bf16(af[i], bfr[j], acc[i][j], 0, 0, 0);
    __builtin_amdgcn_s_setprio(0);
}

__global__ __launch_bounds__(512)
void sim_kernel(const __hip_bfloat16* __restrict__ embb,
                const uint64_t* __restrict__ mask,
                float* __restrict__ psum,
                float* __restrict__ nsum) {
    __shared__ __align__(16) unsigned char lds[49152];   // 3 buffers x (8KB A + 8KB B)
    __shared__ uint64_t rmaskS[128];
    __shared__ uint64_t cmaskS[128];

    // XCD-aware bijective swizzle: 528 = 8 * 66
    const int bid = (int)blockIdx.x;
    int t = (bid & 7) * 66 + (bid >> 3);
    int by = 0;
    while (t >= NTB - by) { t -= NTB - by; ++by; }
    const int bx = by + t;

    const int tid  = threadIdx.x;
    const int lane = tid & 63;
    const int wid  = tid >> 6;          // 0..7
    const int wm   = wid >> 2;          // 0..1 : row half (64 rows)
    const int wn   = wid & 3;           // 0..3 : col quarter (32 cols)

    if (tid < 128)      rmaskS[tid]       = mask[by * 128 + tid];
    else if (tid < 256) cmaskS[tid - 128] = mask[bx * 128 + (tid - 128)];

    f32x4 acc[4][2];
    #pragma unroll
    for (int i = 0; i < 4; ++i)
        #pragma unroll
        for (int j = 0; j < 2; ++j) acc[i][j] = (f32x4)0.0f;

    const size_t arow0 = (size_t)by * 128;
    const size_t brow0 = (size_t)bx * 128;

    unsigned char* bc = lds;            // compute buffer (tile t)
    unsigned char* bn = lds + 16384;    // next (tile t+1)
    unsigned char* bs = lds + 32768;    // stage target (tile t+2)

    // ---- prologue: 2 tiles in flight (4 loads/thread outstanding) ----
    stage_tile(embb, arow0, brow0, 0, bc, tid);
    stage_tile(embb, arow0, brow0, 1, bn, tid);

    // ---- 32 K-phases (BK=32), single barrier per phase, counted vmcnt ----
    #pragma unroll 1
    for (int kb = 0; kb < 31; ++kb) {
        asm volatile("s_waitcnt vmcnt(2)" ::: "memory");   // tile kb landed
        __builtin_amdgcn_s_barrier();                      // also: bs free (read kb-1 done)
        if (kb < 30) stage_tile(embb, arow0, brow0, kb + 2, bs, tid);
        compute_tile(bc, wm, wn, lane, acc);
        unsigned char* tmp = bc; bc = bn; bn = bs; bs = tmp;
    }
    asm volatile("s_waitcnt vmcnt(0)" ::: "memory");
    __builtin_amdgcn_s_barrier();
    compute_tile(bc, wm, wn, lane, acc);

    // C/D layout: col = lane&15, row = (lane>>4)*4 + reg   [m89-verified]
    const int lg = lane >> 4;
    const int lc = lane & 15;

    uint64_t cmR[2];
    #pragma unroll
    for (int nf = 0; nf < 2; ++nf) cmR[nf] = cmaskS[wn * 32 + nf * 16 + lc];

    // ---- exp in place; zero exact-diagonal elements ----
    // |sim| <= 14.3 so exp() spans [6e-7, 1.6e6]: no overflow, max-shift unnecessary
    #pragma unroll
    for (int mf = 0; mf < 4; ++mf)
        #pragma unroll
        for (int nf = 0; nf < 2; ++nf)
            #pragma unroll
            for (int rg = 0; rg < 4; ++rg) {
                const int r_loc = wm * 64 + mf * 16 + lg * 4 + rg;
                const int c_loc = wn * 32 + nf * 16 + lc;
                float e = __expf(acc[mf][nf][rg] * TEMP_INV);
                if ((bx == by) && (r_loc == c_loc)) e = 0.0f;
                acc[mf][nf][rg] = e;
            }

    // ---- row epilogue: plain (pos,neg) sums over this wave's 32 cols ----
    #pragma unroll
    for (int mf = 0; mf < 4; ++mf) {
        #pragma unroll
        for (int rg = 0; rg < 4; ++rg) {
            const int r = wm * 64 + mf * 16 + lg * 4 + rg;
            const uint64_t rm = rmaskS[r];
            float sp = 0.0f, ss = 0.0f;
            #pragma unroll
            for (int nf = 0; nf < 2; ++nf) {
                const float e = acc[mf][nf][rg];
                ss += e;
                if (rm & cmR[nf]) sp += e;
            }
            #pragma unroll
            for (int o = 1; o < 16; o <<= 1) { sp += __shfl_xor(sp, o); ss += __shfl_xor(ss, o); }
            if (lc == 0) {
                atomicAdd(&psum[by * 128 + r], sp);
                atomicAdd(&nsum[by * 128 + r], ss);
            }
        }
    }

    // ---- col epilogue (symmetric contribution), skip on diagonal tiles ----
    if (bx != by) {
        #pragma unroll
        for (int nf = 0; nf < 2; ++nf) {
            const uint64_t cm = cmR[nf];
            float sp = 0.0f, ss = 0.0f;
            #pragma unroll
            for (int mf = 0; mf < 4; ++mf)
                #pragma unroll
                for (int rg = 0; rg < 4; ++rg) {
                    const float e = acc[mf][nf][rg];
                    ss += e;
                    if (rmaskS[wm * 64 + mf * 16 + lg * 4 + rg] & cm) sp += e;
                }
            sp += __shfl_xor(sp, 16); sp += __shfl_xor(sp, 32);
            ss += __shfl_xor(ss, 16); ss += __shfl_xor(ss, 32);
            if (lane < 16) {
                atomicAdd(&psum[bx * 128 + wn * 32 + nf * 16 + lc], sp);
                atomicAdd(&nsum[bx * 128 + wn * 32 + nf * 16 + lc], ss);
            }
        }
    }
}

// ---------------- kernel 3: final scalar (kernel boundary = full visibility) -
__global__ void final_kernel(const float* __restrict__ psum,
                             const float* __restrict__ nsum,
                             const float* __restrict__ w,
                             const float* __restrict__ bce,
                             float* __restrict__ out) {
    const int tid = threadIdx.x;   // 256
    float li = 0.0f, va = 0.0f, bc = 0.0f;
    #pragma unroll 4
    for (int k = 0; k < 16; ++k) {
        const int row = k * 256 + tid;
        const float p = psum[row];
        const float n = nsum[row];
        bc += bce[row];
        if (p > 0.0f) { va += 1.0f; li += -logf(p / (n + 1e-8f)) * w[row]; }
    }
    #pragma unroll
    for (int o = 1; o < 64; o <<= 1) {
        li += __shfl_xor(li, o); va += __shfl_xor(va, o); bc += __shfl_xor(bc, o);
    }
    __shared__ float sl[4], sv[4], sb[4];
    if ((tid & 63) == 0) { sl[tid >> 6] = li; sv[tid >> 6] = va; sb[tid >> 6] = bc; }
    __syncthreads();
    if (tid == 0) {
        const float L = sl[0] + sl[1] + sl[2] + sl[3];
        const float V = sv[0] + sv[1] + sv[2] + sv[3];
        const float B = sb[0] + sb[1] + sb[2] + sb[3];
        out[0] = B / (float)(NROWS * NCLS) + (V > 0.0f ? L / V : 0.0f);
    }
}

extern "C" void kernel_launch(void* const* d_in, const int* in_sizes, int n_in,
                              void* d_out, int out_size, void* d_ws, size_t ws_size,
                              hipStream_t stream) {
    const float* emb    = (const float*)d_in[0];
    const float* logits = (const float*)d_in[1];
    const int*   labels = (const int*)d_in[2];
    float* out = (float*)d_out;

    uint8_t* ws = (uint8_t*)d_ws;
    uint64_t*       mask  = (uint64_t*)(ws);                    // 32 KB
    float*          wrow  = (float*)(ws + 0x8000);              // 16 KB
    float*          bcer  = (float*)(ws + 0xC000);              // 16 KB
    float*          psum  = (float*)(ws + 0x10000);             // 16 KB
    float*          nsum  = (float*)(ws + 0x14000);             // 16 KB
    __hip_bfloat16* embb  = (__hip_bfloat16*)(ws + 0x20000);    // 8 MB

    prep_convert_kernel<<<CONV_BLOCKS + PREP_BLOCKS, 256, 0, stream>>>(
        emb, logits, labels, embb, mask, wrow, bcer, psum, nsum);
    sim_kernel<<<NTRI, 512, 0, stream>>>(embb, mask, psum, nsum);
    final_kernel<<<1, 256, 0, stream>>>(psum, nsum, wrow, bcer, out);
}

// Round 8
// 123.050 us; speedup vs baseline: 1.0345x; 1.0345x over previous
//
#include <hip/hip_runtime.h>
#include <hip/hip_bf16.h>
#include <stdint.h>

#define NROWS 4096
#define DIM   1024
#define NCLS  64
#define NTB2  16            // 4096/256 tile-blocks per axis
#define GRID  256           // NTB2^2 full-matrix blocks (1 per CU)
#define CONV_BLOCKS 2048    // convert part of fused prep kernel
#define PREP_BLOCKS 1024

constexpr float TEMP_INV = 1.0f / 0.07f;

typedef __attribute__((ext_vector_type(8))) short  bf16x8;
typedef __attribute__((ext_vector_type(4))) float  f32x4;

__device__ inline void gload_lds16(const void* g, void* l) {
    __builtin_amdgcn_global_load_lds(
        (const __attribute__((address_space(1))) void*)g,
        (__attribute__((address_space(3))) void*)l, 16, 0, 0);
}

// ---------------- kernel 1: fused convert (bf16 pre-swizzle) + prep ----------
// swizzle: within each 64-elem K-block (8x 16B slots) of a row, slot s stored
// at s ^ (row&7) -- matched by frag_read's XOR. Measured 0 bank conflicts.
__global__ void prep_convert_kernel(const float* __restrict__ emb,
                                    const float* __restrict__ logits,
                                    const int* __restrict__ labels,
                                    __hip_bfloat16* __restrict__ embb,
                                    uint64_t* __restrict__ maskout,
                                    float* __restrict__ wout,
                                    float* __restrict__ bceout,
                                    float* __restrict__ psum,
                                    float* __restrict__ nsum) {
    const int b = blockIdx.x;
    if (b < CONV_BLOCKS) {
        const int t   = b * 256 + threadIdx.x;   // one 16B slot (8 elems) each
        const int row = t >> 7;                  // 128 slots per row
        const int sl  = t & 127;
        const int kb  = sl >> 3;
        const int s   = sl & 7;
        const float* src = emb + (size_t)row * DIM + kb * 64 + s * 8;
        const float4 a  = *(const float4*)src;
        const float4 bb = *(const float4*)(src + 4);
        const int sd = s ^ (row & 7);
        union { __hip_bfloat16 h[8]; float4 v; } u;
        u.h[0] = __float2bfloat16(a.x);  u.h[1] = __float2bfloat16(a.y);
        u.h[2] = __float2bfloat16(a.z);  u.h[3] = __float2bfloat16(a.w);
        u.h[4] = __float2bfloat16(bb.x); u.h[5] = __float2bfloat16(bb.y);
        u.h[6] = __float2bfloat16(bb.z); u.h[7] = __float2bfloat16(bb.w);
        *(float4*)(embb + (size_t)row * DIM + kb * 64 + sd * 8) = u.v;
    } else {
        const int pb   = b - CONV_BLOCKS;
        const int row  = pb * 4 + (threadIdx.x >> 6);
        const int lane = threadIdx.x & 63;
        if (threadIdx.x < 4)       psum[pb * 4 + threadIdx.x] = 0.0f;
        else if (threadIdx.x < 8)  nsum[pb * 4 + threadIdx.x - 4] = 0.0f;

        const float l = logits[row * NCLS + lane];
        const int   y = labels[row * NCLS + lane];
        const float yf = (float)y;

        float bce = fmaxf(l, 0.0f) - l * yf + log1pf(expf(-fabsf(l)));
        const float pr = 1.0f / (1.0f + expf(-l));
        const float ent = -(pr * logf(pr + 1e-8f) + (1.0f - pr) * logf(1.0f - pr + 1e-8f));
        float entw = ent * yf;
        float ycnt = yf;

        #pragma unroll
        for (int off = 32; off; off >>= 1) {
            bce  += __shfl_down(bce, off);
            entw += __shfl_down(entw, off);
            ycnt += __shfl_down(ycnt, off);
        }
        const uint64_t m = __ballot(y != 0);
        if (lane == 0) {
            maskout[row] = m;
            wout[row]    = entw / (ycnt + 1e-8f);
            bceout[row]  = bce;
        }
    }
}

// ---------------- kernel 2: 256x256-tile MFMA sim, counted-vmcnt dbuf --------
// LDS buffer (64KB): A tile [256 rows][64 bf16] at +0, B tile at +32768.
// Row stride 128B = 8 slots of 16B, slots pre-swizzled by (row&7).
__device__ inline bf16x8 frag_read(const unsigned char* tile, int row, int ks, int lane) {
    const int slot = (ks * 4 + (lane >> 4)) ^ (row & 7);
    return *(const bf16x8*)(tile + row * 128 + slot * 16);
}

// 512 threads x 8 loads (4 A-chunks + 4 B-chunks of 64 rows each)
__device__ inline void stage_tile(const __hip_bfloat16* __restrict__ embb,
                                  size_t arow0, size_t brow0, int kb,
                                  unsigned char* buf, int tid) {
    const int r = tid >> 3;            // 0..63
    const int s = (tid & 7) * 8;       // elem offset (pre-swizzled source)
    #pragma unroll
    for (int c = 0; c < 4; ++c) {
        gload_lds16(embb + (arow0 + c * 64 + r) * DIM + kb * 64 + s, buf + c * 8192 + tid * 16);
        gload_lds16(embb + (brow0 + c * 64 + r) * DIM + kb * 64 + s, buf + 32768 + c * 8192 + tid * 16);
    }
}

// wave (wm,wn) computes 128x64 sub-tile: acc[8 row-frags][4 col-frags]
__device__ inline void compute_tile(const unsigned char* buf,
                                    int wm, int wn, int lane, f32x4 acc[8][4]) {
    const unsigned char* As = buf;
    const unsigned char* Bs = buf + 32768;
    __builtin_amdgcn_s_setprio(1);
    #pragma unroll
    for (int ks = 0; ks < 2; ++ks) {
        bf16x8 af[8], bfr[4];
        #pragma unroll
        for (int f = 0; f < 8; ++f)
            af[f] = frag_read(As, wm * 128 + f * 16 + (lane & 15), ks, lane);
        #pragma unroll
        for (int g = 0; g < 4; ++g)
            bfr[g] = frag_read(Bs, wn * 64 + g * 16 + (lane & 15), ks, lane);
        #pragma unroll
        for (int f = 0; f < 8; ++f)
            #pragma unroll
            for (int g = 0; g < 4; ++g)
                acc[f][g] = __builtin_amdgcn_mfma_f32_16x16x32_bf16(af[f], bfr[g], acc[f][g], 0, 0, 0);
    }
    __builtin_amdgcn_s_setprio(0);
}

__global__ __launch_bounds__(512, 2)
void sim_kernel(const __hip_bfloat16* __restrict__ embb,
                const uint64_t* __restrict__ mask,
                float* __restrict__ psum,
                float* __restrict__ nsum) {
    __shared__ __align__(16) unsigned char lds[131072];   // 2 x (32KB A + 32KB B)
    __shared__ uint64_t rmaskS[256];
    __shared__ uint64_t cmaskS[256];

    // XCD-aware bijective swizzle: 256 = 8 * 32 -> each XCD gets 2 row-panels
    const int bid = (int)blockIdx.x;
    const int wg  = (bid & 7) * 32 + (bid >> 3);
    const int by  = wg >> 4;
    const int bx  = wg & 15;

    const int tid  = threadIdx.x;
    const int lane = tid & 63;
    const int wid  = tid >> 6;          // 0..7
    const int wm   = wid >> 2;          // 0..1 : row half (128 rows)
    const int wn   = wid & 3;           // 0..3 : col quarter (64 cols)

    // masks -> LDS before any staging (keeps vmcnt accounting clean)
    if (tid < 256)  rmaskS[tid]       = mask[by * 256 + tid];
    else            cmaskS[tid - 256] = mask[bx * 256 + (tid - 256)];
    __syncthreads();

    f32x4 acc[8][4];
    #pragma unroll
    for (int i = 0; i < 8; ++i)
        #pragma unroll
        for (int j = 0; j < 4; ++j) acc[i][j] = (f32x4)0.0f;

    const size_t arow0 = (size_t)by * 256;
    const size_t brow0 = (size_t)bx * 256;
    unsigned char* buf0 = lds;
    unsigned char* buf1 = lds + 65536;

    // ---- prologue: 2 tiles in flight (16 loads/thread outstanding) ----
    stage_tile(embb, arow0, brow0, 0, buf0, tid);
    stage_tile(embb, arow0, brow0, 1, buf1, tid);

    // ---- counted-vmcnt dbuf: 16 K-tiles (BK=64), never drain in steady state
    #pragma unroll 1
    for (int kb2 = 0; kb2 < 7; ++kb2) {
        asm volatile("s_waitcnt vmcnt(8)" ::: "memory");   // tile 2k landed
        __builtin_amdgcn_s_barrier();
        compute_tile(buf0, wm, wn, lane, acc);
        __builtin_amdgcn_s_barrier();
        stage_tile(embb, arow0, brow0, 2 * kb2 + 2, buf0, tid);
        asm volatile("s_waitcnt vmcnt(8)" ::: "memory");   // tile 2k+1 landed
        __builtin_amdgcn_s_barrier();
        compute_tile(buf1, wm, wn, lane, acc);
        __builtin_amdgcn_s_barrier();
        stage_tile(embb, arow0, brow0, 2 * kb2 + 3, buf1, tid);
    }
    asm volatile("s_waitcnt vmcnt(8)" ::: "memory");       // tile 14
    __builtin_amdgcn_s_barrier();
    compute_tile(buf0, wm, wn, lane, acc);
    asm volatile("s_waitcnt vmcnt(0)" ::: "memory");       // tile 15
    __builtin_amdgcn_s_barrier();
    compute_tile(buf1, wm, wn, lane, acc);

    // C/D layout: col = lane&15, row = (lane>>4)*4 + reg   [m89-verified]
    const int lg = lane >> 4;
    const int lc = lane & 15;

    uint64_t cmR[4];
    #pragma unroll
    for (int nf = 0; nf < 4; ++nf) cmR[nf] = cmaskS[wn * 64 + nf * 16 + lc];

    // ---- exp in place; zero exact-diagonal elements ----
    // |sim| <= 14.3 so exp() spans [6e-7, 1.6e6]: no overflow, max-shift unnecessary
    #pragma unroll
    for (int mf = 0; mf < 8; ++mf)
        #pragma unroll
        for (int nf = 0; nf < 4; ++nf)
            #pragma unroll
            for (int rg = 0; rg < 4; ++rg) {
                const int r_loc = wm * 128 + mf * 16 + lg * 4 + rg;
                const int c_loc = wn * 64 + nf * 16 + lc;
                float e = __expf(acc[mf][nf][rg] * TEMP_INV);
                if ((bx == by) && (r_loc == c_loc)) e = 0.0f;
                acc[mf][nf][rg] = e;
            }

    // ---- row epilogue: (pos,neg) sums over this wave's 64 cols ----
    #pragma unroll
    for (int mf = 0; mf < 8; ++mf) {
        #pragma unroll
        for (int rg = 0; rg < 4; ++rg) {
            const int r = wm * 128 + mf * 16 + lg * 4 + rg;
            const uint64_t rm = rmaskS[r];
            float sp = 0.0f, ss = 0.0f;
            #pragma unroll
            for (int nf = 0; nf < 4; ++nf) {
                const float e = acc[mf][nf][rg];
                ss += e;
                if (rm & cmR[nf]) sp += e;
            }
            #pragma unroll
            for (int o = 1; o < 16; o <<= 1) { sp += __shfl_xor(sp, o); ss += __shfl_xor(ss, o); }
            if (lc == 0) {
                atomicAdd(&psum[by * 256 + r], sp);
                atomicAdd(&nsum[by * 256 + r], ss);
            }
        }
    }
}

// ---------------- kernel 3: final scalar (kernel boundary = full visibility) -
__global__ void final_kernel(const float* __restrict__ psum,
                             const float* __restrict__ nsum,
                             const float* __restrict__ w,
                             const float* __restrict__ bce,
                             float* __restrict__ out) {
    const int tid = threadIdx.x;   // 256
    float li = 0.0f, va = 0.0f, bc = 0.0f;
    #pragma unroll 4
    for (int k = 0; k < 16; ++k) {
        const int row = k * 256 + tid;
        const float p = psum[row];
        const float n = nsum[row];
        bc += bce[row];
        if (p > 0.0f) { va += 1.0f; li += -logf(p / (n + 1e-8f)) * w[row]; }
    }
    #pragma unroll
    for (int o = 1; o < 64; o <<= 1) {
        li += __shfl_xor(li, o); va += __shfl_xor(va, o); bc += __shfl_xor(bc, o);
    }
    __shared__ float sl[4], sv[4], sb[4];
    if ((tid & 63) == 0) { sl[tid >> 6] = li; sv[tid >> 6] = va; sb[tid >> 6] = bc; }
    __syncthreads();
    if (tid == 0) {
        const float L = sl[0] + sl[1] + sl[2] + sl[3];
        const float V = sv[0] + sv[1] + sv[2] + sv[3];
        const float B = sb[0] + sb[1] + sb[2] + sb[3];
        out[0] = B / (float)(NROWS * NCLS) + (V > 0.0f ? L / V : 0.0f);
    }
}

extern "C" void kernel_launch(void* const* d_in, const int* in_sizes, int n_in,
                              void* d_out, int out_size, void* d_ws, size_t ws_size,
                              hipStream_t stream) {
    const float* emb    = (const float*)d_in[0];
    const float* logits = (const float*)d_in[1];
    const int*   labels = (const int*)d_in[2];
    float* out = (float*)d_out;

    uint8_t* ws = (uint8_t*)d_ws;
    uint64_t*       mask  = (uint64_t*)(ws);                    // 32 KB
    float*          wrow  = (float*)(ws + 0x8000);              // 16 KB
    float*          bcer  = (float*)(ws + 0xC000);              // 16 KB
    float*          psum  = (float*)(ws + 0x10000);             // 16 KB
    float*          nsum  = (float*)(ws + 0x14000);             // 16 KB
    __hip_bfloat16* embb  = (__hip_bfloat16*)(ws + 0x20000);    // 8 MB

    prep_convert_kernel<<<CONV_BLOCKS + PREP_BLOCKS, 256, 0, stream>>>(
        emb, logits, labels, embb, mask, wrow, bcer, psum, nsum);
    sim_kernel<<<GRID, 512, 0, stream>>>(embb, mask, psum, nsum);
    final_kernel<<<1, 256, 0, stream>>>(psum, nsum, wrow, bcer, out);
}

// Round 13
// 120.177 us; speedup vs baseline: 1.0592x; 1.0239x over previous
//
#include <hip/hip_runtime.h>
#include <hip/hip_bf16.h>
#include <stdint.h>

#define NROWS 4096
#define DIM   1024
#define NCLS  64
#define NTB2  16            // 4096/256 tile-blocks per axis
#define GRID  256           // full-matrix blocks (1 per CU)
#define CONV_BLOCKS 2048
#define PREP_BLOCKS 1024

constexpr float TEMP_INV = 1.0f / 0.07f;

typedef __attribute__((ext_vector_type(8))) short  bf16x8;
typedef __attribute__((ext_vector_type(4))) float  f32x4;

__device__ inline void gload_lds16(const void* g, void* l) {
    __builtin_amdgcn_global_load_lds(
        (const __attribute__((address_space(1))) void*)g,
        (__attribute__((address_space(3))) void*)l, 16, 0, 0);
}

// ---------------- kernel 1: fused convert (bf16 pre-swizzle) + prep ----------
// swizzle: within each 64-elem K-block (8x 16B slots) of a row, slot s stored
// at s ^ (row&7) -- matched by frag_read's XOR. Measured 0 bank conflicts.
__global__ void prep_convert_kernel(const float* __restrict__ emb,
                                    const float* __restrict__ logits,
                                    const int* __restrict__ labels,
                                    __hip_bfloat16* __restrict__ embb,
                                    uint64_t* __restrict__ maskout,
                                    float* __restrict__ wout,
                                    float* __restrict__ bceout,
                                    float* __restrict__ psum,
                                    float* __restrict__ nsum) {
    const int b = blockIdx.x;
    if (b < CONV_BLOCKS) {
        const int t   = b * 256 + threadIdx.x;   // one 16B slot (8 elems) each
        const int row = t >> 7;                  // 128 slots per row
        const int sl  = t & 127;
        const int kb  = sl >> 3;
        const int s   = sl & 7;
        const float* src = emb + (size_t)row * DIM + kb * 64 + s * 8;
        const float4 a  = *(const float4*)src;
        const float4 bb = *(const float4*)(src + 4);
        const int sd = s ^ (row & 7);
        union { __hip_bfloat16 h[8]; float4 v; } u;
        u.h[0] = __float2bfloat16(a.x);  u.h[1] = __float2bfloat16(a.y);
        u.h[2] = __float2bfloat16(a.z);  u.h[3] = __float2bfloat16(a.w);
        u.h[4] = __float2bfloat16(bb.x); u.h[5] = __float2bfloat16(bb.y);
        u.h[6] = __float2bfloat16(bb.z); u.h[7] = __float2bfloat16(bb.w);
        *(float4*)(embb + (size_t)row * DIM + kb * 64 + sd * 8) = u.v;
    } else {
        const int pb   = b - CONV_BLOCKS;
        const int row  = pb * 4 + (threadIdx.x >> 6);
        const int lane = threadIdx.x & 63;
        if (threadIdx.x < 4)       psum[pb * 4 + threadIdx.x] = 0.0f;
        else if (threadIdx.x < 8)  nsum[pb * 4 + threadIdx.x - 4] = 0.0f;

        const float l = logits[row * NCLS + lane];
        const int   y = labels[row * NCLS + lane];
        const float yf = (float)y;

        float bce = fmaxf(l, 0.0f) - l * yf + log1pf(expf(-fabsf(l)));
        const float pr = 1.0f / (1.0f + expf(-l));
        const float ent = -(pr * logf(pr + 1e-8f) + (1.0f - pr) * logf(1.0f - pr + 1e-8f));
        float entw = ent * yf;
        float ycnt = yf;

        #pragma unroll
        for (int off = 32; off; off >>= 1) {
            bce  += __shfl_down(bce, off);
            entw += __shfl_down(entw, off);
            ycnt += __shfl_down(ycnt, off);
        }
        const uint64_t m = __ballot(y != 0);
        if (lane == 0) {
            maskout[row] = m;
            wout[row]    = entw / (ycnt + 1e-8f);
            bceout[row]  = bce;
        }
    }
}

// ---------------- kernel 2: 256x256 MFMA sim, 4-quadrant-phase pipeline ------
// LDS buffer (64KB): A [256 rows][64 bf16] at +0 (4 chunks of 64 rows, 8KB
// each), B at +32768. Row stride 128B = 8 x 16B slots, pre-swizzled (row&7).
__device__ inline bf16x8 frag_read(const unsigned char* tile, int row, int ks, int lane) {
    const int slot = (ks * 4 + (lane >> 4)) ^ (row & 7);
    return *(const bf16x8*)(tile + row * 128 + slot * 16);
}

// stage 2 of 8 chunks (k0 compile-time): chunks 0-3 = A rows k*64.., 4-7 = B
__device__ inline void stage2(const __hip_bfloat16* __restrict__ embb,
                              size_t arow0, size_t brow0, int kb,
                              unsigned char* buf, int tid, int k0) {
    const int r = tid >> 3;
    const int s = (tid & 7) * 8;
    #pragma unroll
    for (int k = k0; k < k0 + 2; ++k) {
        if (k < 4)
            gload_lds16(embb + (arow0 + k * 64 + r) * DIM + kb * 64 + s,
                        buf + k * 8192 + tid * 16);
        else
            gload_lds16(embb + (brow0 + (k - 4) * 64 + r) * DIM + kb * 64 + s,
                        buf + 32768 + (k - 4) * 8192 + tid * 16);
    }
}

#define READ_A(H)                                                               \
    _Pragma("unroll") for (int i = 0; i < 4; ++i)                               \
        _Pragma("unroll") for (int ks = 0; ks < 2; ++ks)                        \
            af[i][ks] = frag_read(bufc, wm * 128 + (H) * 64 + i * 16 + lcol, ks, lane);

#define READ_B(V)                                                               \
    _Pragma("unroll") for (int j = 0; j < 2; ++j)                               \
        _Pragma("unroll") for (int ks = 0; ks < 2; ++ks)                        \
            bfv[j][ks] = frag_read(bufc + 32768, wn * 64 + (V) * 32 + j * 16 + lcol, ks, lane);

#define PHASE_MFMA(H, V)                                                        \
    __builtin_amdgcn_s_barrier();                                               \
    __builtin_amdgcn_sched_barrier(0);                                          \
    __builtin_amdgcn_s_setprio(1);                                              \
    _Pragma("unroll") for (int ks = 0; ks < 2; ++ks)                            \
        _Pragma("unroll") for (int i = 0; i < 4; ++i)                           \
            _Pragma("unroll") for (int j = 0; j < 2; ++j)                       \
                acc[(H) * 4 + i][(V) * 2 + j] = __builtin_amdgcn_mfma_f32_16x16x32_bf16( \
                    af[i][ks], bfv[j][ks], acc[(H) * 4 + i][(V) * 2 + j], 0, 0, 0); \
    __builtin_amdgcn_s_setprio(0);

__global__ __launch_bounds__(512, 2)
void sim_kernel(const __hip_bfloat16* __restrict__ embb,
                const uint64_t* __restrict__ mask,
                float* __restrict__ psum,
                float* __restrict__ nsum) {
    __shared__ __align__(16) unsigned char lds[131072];   // 2 x (32KB A + 32KB B)
    __shared__ uint64_t rmaskS[256];
    __shared__ uint64_t cmaskS[256];

    // XCD-aware bijective swizzle: 256 = 8 * 32
    const int bid = (int)blockIdx.x;
    const int wg  = (bid & 7) * 32 + (bid >> 3);
    const int by  = wg >> 4;
    const int bx  = wg & 15;

    const int tid  = threadIdx.x;
    const int lane = tid & 63;
    const int lcol = lane & 15;
    const int wid  = tid >> 6;          // 0..7
    const int wm   = wid >> 2;          // 0..1 : row half (128 rows)
    const int wn   = wid & 3;           // 0..3 : col quarter (64 cols)

    if (tid < 256)  rmaskS[tid]       = mask[by * 256 + tid];
    else            cmaskS[tid - 256] = mask[bx * 256 + (tid - 256)];
    __syncthreads();   // masks visible before main loop (prologue only)

    f32x4 acc[8][4];
    #pragma unroll
    for (int i = 0; i < 8; ++i)
        #pragma unroll
        for (int j = 0; j < 4; ++j) acc[i][j] = (f32x4)0.0f;

    const size_t arow0 = (size_t)by * 256;
    const size_t brow0 = (size_t)bx * 256;
    unsigned char* bufc = lds;            // compute buffer (tile t)
    unsigned char* bufn = lds + 65536;    // stage target (tile t+1)

    // ---- prologue: stage tile 0 completely ----
    stage2(embb, arow0, brow0, 0, bufc, tid, 0);
    stage2(embb, arow0, brow0, 0, bufc, tid, 2);
    stage2(embb, arow0, brow0, 0, bufc, tid, 4);
    stage2(embb, arow0, brow0, 0, bufc, tid, 6);

    bf16x8 af[4][2];    // A frags, current h-half
    bf16x8 bfv[2][2];   // B frags, current v-half

    // ---- 16 K-tiles, 4 quadrant-phases each ----
    #pragma unroll 1
    for (int t = 0; t < 16; ++t) {
        // boundary: tile t fully landed (t+1 not yet issued -> no overlap lost)
        asm volatile("s_waitcnt vmcnt(0)" ::: "memory");
        __builtin_amdgcn_s_barrier();
        const bool more = (t < 15);
        const int  nkb  = t + 1;

        // phase 0: quadrant (h=0, v=0)
        READ_A(0)
        READ_B(0)
        if (more) stage2(embb, arow0, brow0, nkb, bufn, tid, 0);
        PHASE_MFMA(0, 0)

        // phase 1: quadrant (h=0, v=1)  [A reused]
        READ_B(1)
        if (more) stage2(embb, arow0, brow0, nkb, bufn, tid, 2);
        PHASE_MFMA(0, 1)

        // phase 2: quadrant (h=1, v=1)  [B reused]
        READ_A(1)
        if (more) stage2(embb, arow0, brow0, nkb, bufn, tid, 4);
        PHASE_MFMA(1, 1)

        // phase 3: quadrant (h=1, v=0)
        READ_B(0)
        if (more) stage2(embb, arow0, brow0, nkb, bufn, tid, 6);
        PHASE_MFMA(1, 0)

        unsigned char* tmp = bufc; bufc = bufn; bufn = tmp;
    }

    // C/D layout: col = lane&15, row = (lane>>4)*4 + reg   [m89-verified]
    const int lg = lane >> 4;
    const int lc = lcol;

    uint64_t cmR[4];
    #pragma unroll
    for (int nf = 0; nf < 4; ++nf) cmR[nf] = cmaskS[wn * 64 + nf * 16 + lc];

    // ---- exp in place; zero exact-diagonal elements ----
    // |sim| <= 14.3 so exp() spans [6e-7, 1.6e6]: no overflow, no max-shift
    #pragma unroll
    for (int mf = 0; mf < 8; ++mf)
        #pragma unroll
        for (int nf = 0; nf < 4; ++nf)
            #pragma unroll
            for (int rg = 0; rg < 4; ++rg) {
                const int r_loc = wm * 128 + mf * 16 + lg * 4 + rg;
                const int c_loc = wn * 64 + nf * 16 + lc;
                float e = __expf(acc[mf][nf][rg] * TEMP_INV);
                if ((bx == by) && (r_loc == c_loc)) e = 0.0f;
                acc[mf][nf][rg] = e;
            }

    // ---- row epilogue: (pos,neg) sums over this wave's 64 cols ----
    #pragma unroll
    for (int mf = 0; mf < 8; ++mf) {
        #pragma unroll
        for (int rg = 0; rg < 4; ++rg) {
            const int r = wm * 128 + mf * 16 + lg * 4 + rg;
            const uint64_t rm = rmaskS[r];
            float sp = 0.0f, ss = 0.0f;
            #pragma unroll
            for (int nf = 0; nf < 4; ++nf) {
                const float e = acc[mf][nf][rg];
                ss += e;
                if (rm & cmR[nf]) sp += e;
            }
            #pragma unroll
            for (int o = 1; o < 16; o <<= 1) { sp += __shfl_xor(sp, o); ss += __shfl_xor(ss, o); }
            if (lc == 0) {
                atomicAdd(&psum[by * 256 + r], sp);
                atomicAdd(&nsum[by * 256 + r], ss);
            }
        }
    }
}

// ---------------- kernel 3: final scalar (kernel boundary = full visibility) -
__global__ void final_kernel(const float* __restrict__ psum,
                             const float* __restrict__ nsum,
                             const float* __restrict__ w,
                             const float* __restrict__ bce,
                             float* __restrict__ out) {
    const int tid = threadIdx.x;   // 256
    float li = 0.0f, va = 0.0f, bc = 0.0f;
    #pragma unroll 4
    for (int k = 0; k < 16; ++k) {
        const int row = k * 256 + tid;
        const float p = psum[row];
        const float n = nsum[row];
        bc += bce[row];
        if (p > 0.0f) { va += 1.0f; li += -logf(p / (n + 1e-8f)) * w[row]; }
    }
    #pragma unroll
    for (int o = 1; o < 64; o <<= 1) {
        li += __shfl_xor(li, o); va += __shfl_xor(va, o); bc += __shfl_xor(bc, o);
    }
    __shared__ float sl[4], sv[4], sb[4];
    if ((tid & 63) == 0) { sl[tid >> 6] = li; sv[tid >> 6] = va; sb[tid >> 6] = bc; }
    __syncthreads();
    if (tid == 0) {
        const float L = sl[0] + sl[1] + sl[2] + sl[3];
        const float V = sv[0] + sv[1] + sv[2] + sv[3];
        const float B = sb[0] + sb[1] + sb[2] + sb[3];
        out[0] = B / (float)(NROWS * NCLS) + (V > 0.0f ? L / V : 0.0f);
    }
}

extern "C" void kernel_launch(void* const* d_in, const int* in_sizes, int n_in,
                              void* d_out, int out_size, void* d_ws, size_t ws_size,
                              hipStream_t stream) {
    const float* emb    = (const float*)d_in[0];
    const float* logits = (const float*)d_in[1];
    const int*   labels = (const int*)d_in[2];
    float* out = (float*)d_out;

    uint8_t* ws = (uint8_t*)d_ws;
    uint64_t*       mask  = (uint64_t*)(ws);                    // 32 KB
    float*          wrow  = (float*)(ws + 0x8000);              // 16 KB
    float*          bcer  = (float*)(ws + 0xC000);              // 16 KB
    float*          psum  = (float*)(ws + 0x10000);             // 16 KB
    float*          nsum  = (float*)(ws + 0x14000);             // 16 KB
    __hip_bfloat16* embb  = (__hip_bfloat16*)(ws + 0x20000);    // 8 MB

    prep_convert_kernel<<<CONV_BLOCKS + PREP_BLOCKS, 256, 0, stream>>>(
        emb, logits, labels, embb, mask, wrow, bcer, psum, nsum);
    sim_kernel<<<GRID, 512, 0, stream>>>(embb, mask, psum, nsum);
    final_kernel<<<1, 256, 0, stream>>>(psum, nsum, wrow, bcer, out);
}